// Round 1
// baseline (1532.566 us; speedup 1.0000x reference)
//
#include <hip/hip_runtime.h>
#include <stdint.h>

#define PP 5
#define EE 400000
#define NN 50000
#define PN (PP*NN)            // 250000 rows (protocol,node)
#define EPT (PP*EE)           // 2,000,000 edges total
#define K1B 320
#define K1NB (EE/K1B)         // 1250 blocks per protocol
#define SCAN_NB ((PN+1023)/1024)  // 245

typedef unsigned int u32;
typedef unsigned short u16;

__device__ __forceinline__ u16 f2bf(float x){
  u32 u = __float_as_uint(x);
  u32 r = (u + 0x7fffu + ((u>>16)&1u))>>16;
  return (u16)r;
}
__device__ __forceinline__ float bf2f(u32 b){ return __uint_as_float(b<<16); }
__device__ __forceinline__ float lrelu(float x){ return fmaxf(x,0.f)+0.2f*fminf(x,0.f); }

// ---------------- utility ----------------
__global__ __launch_bounds__(256) void k_zero(u32* p, int n){
  int i=blockIdx.x*256+threadIdx.x; if(i<n) p[i]=0u;
}

// ---------------- CSR build ----------------
__global__ __launch_bounds__(256) void k_hist(const int* __restrict__ ei, u32* __restrict__ deg){
  int p=blockIdx.y, e=blockIdx.x*256+threadIdx.x;
  if(e<EE){
    int d = ei[(size_t)(p*2+1)*EE + e];
    atomicAdd(&deg[p*NN+d],1u);
  }
}

__global__ __launch_bounds__(256) void k_scan1(const u32* __restrict__ deg, u32* __restrict__ off, u32* __restrict__ bsum){
  __shared__ u32 s[256];
  int b=blockIdx.x, t=threadIdx.x;
  int base=b*1024+t*4;
  u32 v0=(base  <PN)?deg[base  ]:0u;
  u32 v1=(base+1<PN)?deg[base+1]:0u;
  u32 v2=(base+2<PN)?deg[base+2]:0u;
  u32 v3=(base+3<PN)?deg[base+3]:0u;
  u32 tot=v0+v1+v2+v3;
  s[t]=tot; __syncthreads();
  for(int o=1;o<256;o<<=1){
    u32 x=(t>=o)?s[t-o]:0u;
    __syncthreads();
    s[t]+=x;
    __syncthreads();
  }
  u32 excl=s[t]-tot;
  if(base  <PN) off[base  ]=excl;
  if(base+1<PN) off[base+1]=excl+v0;
  if(base+2<PN) off[base+2]=excl+v0+v1;
  if(base+3<PN) off[base+3]=excl+v0+v1+v2;
  if(t==255) bsum[b]=s[255];
}

__global__ __launch_bounds__(256) void k_scan2(const u32* __restrict__ bsum, u32* __restrict__ bsumX){
  __shared__ u32 s[256];
  int t=threadIdx.x;
  u32 v=(t<SCAN_NB)?bsum[t]:0u;
  s[t]=v; __syncthreads();
  for(int o=1;o<256;o<<=1){
    u32 x=(t>=o)?s[t-o]:0u;
    __syncthreads();
    s[t]+=x;
    __syncthreads();
  }
  if(t<SCAN_NB) bsumX[t]=s[t]-v;
}

__global__ __launch_bounds__(256) void k_scan3(u32* __restrict__ off, const u32* __restrict__ bsumX, u32* __restrict__ cursor){
  int i=blockIdx.x*256+threadIdx.x;
  if(i<PN){
    u32 v=off[i]+bsumX[i>>10];
    off[i]=v; cursor[i]=v;
  }
  if(i==0) off[PN]=(u32)EPT;
}

__global__ __launch_bounds__(256) void k_scatter(const int* __restrict__ ei, u32* __restrict__ cursor,
                                                 u32* __restrict__ srcs, u32* __restrict__ perm){
  int p=blockIdx.y, e=blockIdx.x*256+threadIdx.x;
  if(e<EE){
    int s = ei[(size_t)(p*2  )*EE + e];
    int d = ei[(size_t)(p*2+1)*EE + e];
    u32 pos = atomicAdd(&cursor[p*NN+d],1u);
    srcs[pos]=(u32)s;
    perm[(size_t)p*EE+e]=pos;
  }
}

// ---------------- edge-feature projection (all 6 layers at once) ----------------
// LDS We layout: 52-wide rows, per-layer col offsets {0,8,16,20,28,36}, pads zeroed.
__global__ __launch_bounds__(K1B) void k_eproj(
    const float* __restrict__ ea, const u32* __restrict__ perm,
    const float* __restrict__ we0, const float* __restrict__ we1,
    const float* __restrict__ we2, const float* __restrict__ we3,
    const float* __restrict__ we4, const float* __restrict__ we5,
    u16* __restrict__ ep0, u16* __restrict__ ep1, u16* __restrict__ ep2,
    u16* __restrict__ ep3, u16* __restrict__ ep4, u16* __restrict__ ep5,
    float* __restrict__ bpart)
{
  __shared__ float sEA[K1B*35];
  __shared__ float sWE[35*52];
  const int t=threadIdx.x, bx=blockIdx.x, p=blockIdx.y;
  {
    const float4* g=(const float4*)(ea + ((size_t)p*EE + (size_t)bx*K1B)*35);
    float4* s4=(float4*)sEA;
    #pragma unroll
    for(int c=0;c<9;c++){ int i=t+c*K1B; if(i<2800) s4[i]=g[i]; }
  }
  for(int i=t;i<35*52;i+=K1B) sWE[i]=0.f;
  __syncthreads();
  { const float* w=we0+(size_t)p*280; for(int i=t;i<280;i+=K1B){int k=i>>3,f=i&7;  sWE[k*52+ 0+f]=w[i];} }
  { const float* w=we1+(size_t)p*280; for(int i=t;i<280;i+=K1B){int k=i>>3,f=i&7;  sWE[k*52+ 8+f]=w[i];} }
  { const float* w=we2+(size_t)p*70;  for(int i=t;i<70; i+=K1B){int k=i>>1,f=i&1;  sWE[k*52+16+f]=w[i];} }
  { const float* w=we3+(size_t)p*280; for(int i=t;i<280;i+=K1B){int k=i>>3,f=i&7;  sWE[k*52+20+f]=w[i];} }
  { const float* w=we4+(size_t)p*280; for(int i=t;i<280;i+=K1B){int k=i>>3,f=i&7;  sWE[k*52+28+f]=w[i];} }
  { const float* w=we5+(size_t)p*525; for(int i=t;i<525;i+=K1B){int k=i/15,f=i-k*15;sWE[k*52+36+f]=w[i];} }
  __syncthreads();

  float rea[35];
  #pragma unroll
  for(int k=0;k<35;k++) rea[k]=sEA[t*35+k];

  const u32 pos = perm[(size_t)p*EE + (size_t)bx*K1B + t];

  // 8-wide layers
  #define COMP8(WO, EP_) { \
    float4 a0={0,0,0,0}, a1={0,0,0,0}; \
    _Pragma("unroll") \
    for(int k=0;k<35;k++){ float v=rea[k]; \
      const float4* wr4=(const float4*)&sWE[k*52+(WO)]; \
      float4 w0=wr4[0], w1=wr4[1]; \
      a0.x+=v*w0.x; a0.y+=v*w0.y; a0.z+=v*w0.z; a0.w+=v*w0.w; \
      a1.x+=v*w1.x; a1.y+=v*w1.y; a1.z+=v*w1.z; a1.w+=v*w1.w; } \
    uint4 q; \
    q.x=(u32)f2bf(a0.x)|((u32)f2bf(a0.y)<<16); \
    q.y=(u32)f2bf(a0.z)|((u32)f2bf(a0.w)<<16); \
    q.z=(u32)f2bf(a1.x)|((u32)f2bf(a1.y)<<16); \
    q.w=(u32)f2bf(a1.z)|((u32)f2bf(a1.w)<<16); \
    ((uint4*)(EP_))[pos]=q; }

  COMP8(0,  ep0)
  COMP8(8,  ep1)
  { // e3: 2-wide
    float ax=0.f, ay=0.f;
    #pragma unroll
    for(int k=0;k<35;k++){ float v=rea[k]; ax+=v*sWE[k*52+16]; ay+=v*sWE[k*52+17]; }
    ((u32*)ep2)[pos]=(u32)f2bf(ax)|((u32)f2bf(ay)<<16);
  }
  COMP8(20, ep3)
  COMP8(28, ep4)
  { // d3: 15-wide (padded to 16, pad col zeroed)
    float4 a0={0,0,0,0},a1={0,0,0,0},a2={0,0,0,0},a3={0,0,0,0};
    #pragma unroll
    for(int k=0;k<35;k++){ float v=rea[k];
      const float4* wr4=(const float4*)&sWE[k*52+36];
      float4 w0=wr4[0],w1=wr4[1],w2=wr4[2],w3=wr4[3];
      a0.x+=v*w0.x; a0.y+=v*w0.y; a0.z+=v*w0.z; a0.w+=v*w0.w;
      a1.x+=v*w1.x; a1.y+=v*w1.y; a1.z+=v*w1.z; a1.w+=v*w1.w;
      a2.x+=v*w2.x; a2.y+=v*w2.y; a2.z+=v*w2.z; a2.w+=v*w2.w;
      a3.x+=v*w3.x; a3.y+=v*w3.y; a3.z+=v*w3.z; a3.w+=v*w3.w; }
    uint4 q0,q1;
    q0.x=(u32)f2bf(a0.x)|((u32)f2bf(a0.y)<<16);
    q0.y=(u32)f2bf(a0.z)|((u32)f2bf(a0.w)<<16);
    q0.z=(u32)f2bf(a1.x)|((u32)f2bf(a1.y)<<16);
    q0.w=(u32)f2bf(a1.z)|((u32)f2bf(a1.w)<<16);
    q1.x=(u32)f2bf(a2.x)|((u32)f2bf(a2.y)<<16);
    q1.y=(u32)f2bf(a2.z)|((u32)f2bf(a2.w)<<16);
    q1.z=(u32)f2bf(a3.x)|((u32)f2bf(a3.y)<<16);
    q1.w=(u32)f2bf(a3.z)|((u32)f2bf(a3.w)<<16);
    uint4* dst=(uint4*)ep5;
    dst[(size_t)pos*2  ]=q0;
    dst[(size_t)pos*2+1]=q1;
  }
  #undef COMP8

  // per-block column sums of ea for the edge-feature mean (self loops)
  if(t<35){
    float s=0.f;
    #pragma unroll 8
    for(int r=0;r<K1B;r++) s+=sEA[r*35+t];
    bpart[((size_t)p*K1NB+bx)*35+t]=s;
  }
}

__global__ __launch_bounds__(1024) void k_selfvec(const float* __restrict__ bpart,
    const float* __restrict__ we0, const float* __restrict__ we1,
    const float* __restrict__ we2, const float* __restrict__ we3,
    const float* __restrict__ we4, const float* __restrict__ we5,
    float* __restrict__ selfvec)
{
  __shared__ float partLDS[4*175];
  __shared__ float meanv[175];
  int t=threadIdx.x;
  if(t<700){
    int j=t%175, q=t/175;
    int p=j/35, k=j-35*p;
    int b0=q*313, b1=b0+313; if(b1>K1NB) b1=K1NB;
    float s=0.f;
    for(int b=b0;b<b1;b++) s+=bpart[((size_t)p*K1NB+b)*35+k];
    partLDS[q*175+j]=s;
  }
  __syncthreads();
  if(t<175) meanv[t]=(partLDS[t]+partLDS[175+t]+partLDS[350+t]+partLDS[525+t])*(1.f/EE);
  __syncthreads();
  #define SV(L_,FO_,WPTR_) if(t<5*(FO_)){ int p=t/(FO_), f=t-p*(FO_); \
    const float* w=(WPTR_)+(size_t)p*35*(FO_); \
    float s=0.f; for(int k=0;k<35;k++) s+=meanv[p*35+k]*w[k*(FO_)+f]; \
    selfvec[((L_)*5+p)*16+f]=s; }
  SV(0,8,we0) SV(1,8,we1) SV(2,2,we2) SV(3,8,we3) SV(4,8,we4) SV(5,15,we5)
  #undef SV
}

// ---------------- per-layer node projection ----------------
template<int FI,int FO>
__global__ __launch_bounds__(256) void k_proj(
  const float* __restrict__ h, int hs,
  const float* __restrict__ wl, const float* __restrict__ wr,
  float* __restrict__ xl, float* __restrict__ xr)
{
  __shared__ float sl[FI*FO], sr[FI*FO];
  const int t=threadIdx.x, p=blockIdx.y;
  if(t<FI*FO){ sl[t]=wl[(size_t)p*FI*FO+t]; sr[t]=wr[(size_t)p*FI*FO+t]; }
  __syncthreads();
  const int n=blockIdx.x*256+t;
  if(n>=NN) return;
  float hv[FI];
  #pragma unroll
  for(int k=0;k<FI;k++) hv[k]=h[(size_t)n*hs+k];
  const size_t base=((size_t)p*NN+n)*16;
  #pragma unroll
  for(int f=0;f<FO;f++){
    float al=0.f, ar=0.f;
    #pragma unroll
    for(int k=0;k<FI;k++){ al+=hv[k]*sl[k*FO+f]; ar+=hv[k]*sr[k*FO+f]; }
    xl[base+f]=al; xr[base+f]=ar;
  }
}

template<int FO>
__device__ __forceinline__ void load_row(const float* __restrict__ g, float* arr){
  if constexpr(FO==2){
    float2 v=*(const float2*)g; arr[0]=v.x; arr[1]=v.y;
  } else {
    #pragma unroll
    for(int c=0;c<(FO+3)/4;c++){
      float4 v=((const float4*)g)[c];
      arr[4*c]=v.x;
      if(4*c+1<FO) arr[4*c+1]=v.y;
      if(4*c+2<FO) arr[4*c+2]=v.z;
      if(4*c+3<FO) arr[4*c+3]=v.w;
    }
  }
}

// ---------------- per-layer gather aggregation (4 lanes per row) ----------------
template<int FO,int EPAD>
__global__ __launch_bounds__(256) void k_agg(
  const float* __restrict__ xl, const float* __restrict__ xr,
  const u32* __restrict__ off, const u32* __restrict__ srcs,
  const u16* __restrict__ ep, const float* __restrict__ avec,
  const float* __restrict__ selfv, float* __restrict__ partial)
{
  const int t=threadIdx.x, p=blockIdx.y;
  const int n=blockIdx.x*64+(t>>2), sub=t&3;
  if(n>=NN) return;
  const int r=p*NN+n;
  float av[FO], xln[FO], xrn[FO];
  #pragma unroll
  for(int f=0;f<FO;f++) av[f]=avec[p*FO+f];
  load_row<FO>(xl+(size_t)r*16, xln);
  load_row<FO>(xr+(size_t)r*16, xrn);

  float den=0.f, num[FO];
  #pragma unroll
  for(int f=0;f<FO;f++) num[f]=0.f;
  if(sub==0){
    float e=0.f;
    #pragma unroll
    for(int f=0;f<FO;f++){ float m=xln[f]+xrn[f]+selfv[p*16+f]; e+=lrelu(m)*av[f]; }
    float ex=__expf(e);
    den=ex;
    #pragma unroll
    for(int f=0;f<FO;f++) num[f]=ex*xln[f];
  }
  const u32 j1=off[r+1];
  for(u32 j=off[r]+sub;j<j1;j+=4){
    const u32 s=srcs[j];
    float epv[FO];
    if constexpr(EPAD==8){
      uint4 q=*(const uint4*)(ep+(size_t)j*8);
      epv[0]=bf2f(q.x&0xffffu); epv[1]=bf2f(q.x>>16);
      epv[2]=bf2f(q.y&0xffffu); epv[3]=bf2f(q.y>>16);
      epv[4]=bf2f(q.z&0xffffu); epv[5]=bf2f(q.z>>16);
      epv[6]=bf2f(q.w&0xffffu); epv[7]=bf2f(q.w>>16);
    } else if constexpr(EPAD==2){
      u32 q=*(const u32*)(ep+(size_t)j*2);
      epv[0]=bf2f(q&0xffffu); epv[1]=bf2f(q>>16);
    } else {
      const uint4* qq=(const uint4*)(ep+(size_t)j*16);
      uint4 q0=qq[0], q1=qq[1];
      u32 w[8]={q0.x,q0.y,q0.z,q0.w,q1.x,q1.y,q1.z,q1.w};
      #pragma unroll
      for(int i=0;i<8;i++){
        if(2*i  <FO) epv[2*i  ]=bf2f(w[i]&0xffffu);
        if(2*i+1<FO) epv[2*i+1]=bf2f(w[i]>>16);
      }
    }
    float xls[FO];
    load_row<FO>(xl+((size_t)p*NN+s)*16, xls);
    float e=0.f;
    #pragma unroll
    for(int f=0;f<FO;f++){ float m=xls[f]+xrn[f]+epv[f]; e+=lrelu(m)*av[f]; }
    const float ex=__expf(e);
    den+=ex;
    #pragma unroll
    for(int f=0;f<FO;f++) num[f]+=ex*xls[f];
  }
  den+=__shfl_xor(den,1); den+=__shfl_xor(den,2);
  #pragma unroll
  for(int f=0;f<FO;f++){ num[f]+=__shfl_xor(num[f],1); num[f]+=__shfl_xor(num[f],2); }
  if(sub==0){
    const float inv=1.f/den;
    float* dst=partial+(size_t)r*16;
    #pragma unroll
    for(int f=0;f<FO;f++) dst[f]=num[f]*inv;
  }
}

// ---------------- combine protocols + bias + activation ----------------
template<int FO,bool RELU,bool OUT15>
__global__ __launch_bounds__(256) void k_final(
  const float* __restrict__ partial, const float* __restrict__ b,
  float* __restrict__ hout)
{
  const int n=blockIdx.x*256+threadIdx.x;
  if(n>=NN) return;
  float s[FO];
  #pragma unroll
  for(int f=0;f<FO;f++) s[f]=0.f;
  #pragma unroll
  for(int p=0;p<PP;p++){
    const float* src=partial+((size_t)p*NN+n)*16;
    #pragma unroll
    for(int f=0;f<FO;f++) s[f]+=src[f];
  }
  #pragma unroll
  for(int p=0;p<PP;p++){
    #pragma unroll
    for(int f=0;f<FO;f++) s[f]+=b[p*FO+f];
  }
  #pragma unroll
  for(int f=0;f<FO;f++){
    float v=RELU?fmaxf(s[f],0.f):s[f];
    hout[(size_t)n*(OUT15?15:16)+f]=v;
  }
}

// ---------------- launch ----------------
extern "C" void kernel_launch(void* const* d_in, const int* in_sizes, int n_in,
                              void* d_out, int out_size, void* d_ws, size_t ws_size,
                              hipStream_t stream)
{
  const float* x =(const float*)d_in[0];
  const float* ea=(const float*)d_in[1];
  const int*   ei=(const int*)d_in[2];
  auto W=[&](int l,int k)->const float*{ return (const float*)d_in[3+5*l+k]; };

  char* base=(char*)d_ws; size_t cur=0;
  auto alloc=[&](size_t bytes)->char*{ char* pp=base+cur; cur=(cur+bytes+255)&~(size_t)255; return pp; };
  u32*  deg    =(u32*) alloc((size_t)PN*4);
  u32*  off    =(u32*) alloc((size_t)(PN+1)*4);
  u32*  cursor =(u32*) alloc((size_t)PN*4);
  u32*  bsum   =(u32*) alloc(256*4);
  u32*  bsumX  =(u32*) alloc(256*4);
  u32*  srcs   =(u32*) alloc((size_t)EPT*4);
  u32*  perm   =(u32*) alloc((size_t)EPT*4);
  float* bpart =(float*)alloc((size_t)PP*K1NB*35*4);
  float* selfvec=(float*)alloc(6*PP*16*4);
  float* xl    =(float*)alloc((size_t)PN*16*4);
  float* xr    =(float*)alloc((size_t)PN*16*4);
  float* partial=(float*)alloc((size_t)PN*16*4);
  float* hA    =(float*)alloc((size_t)NN*16*4);
  float* hB    =(float*)alloc((size_t)NN*16*4);
  u16*  ep0    =(u16*) alloc((size_t)EPT*8*2);
  u16*  ep1    =(u16*) alloc((size_t)EPT*8*2);
  u16*  ep2    =(u16*) alloc((size_t)EPT*2*2);
  u16*  ep3    =(u16*) alloc((size_t)EPT*8*2);
  u16*  ep4    =(u16*) alloc((size_t)EPT*8*2);
  u16*  ep5    =(u16*) alloc((size_t)EPT*16*2);
  (void)ws_size; (void)in_sizes; (void)n_in; (void)out_size;

  dim3 b256(256);
  k_zero   <<<dim3((PN+255)/256),b256,0,stream>>>(deg,PN);
  k_hist   <<<dim3((EE+255)/256,PP),b256,0,stream>>>(ei,deg);
  k_scan1  <<<dim3(SCAN_NB),b256,0,stream>>>(deg,off,bsum);
  k_scan2  <<<dim3(1),b256,0,stream>>>(bsum,bsumX);
  k_scan3  <<<dim3((PN+255)/256),b256,0,stream>>>(off,bsumX,cursor);
  k_scatter<<<dim3((EE+255)/256,PP),b256,0,stream>>>(ei,cursor,srcs,perm);
  k_eproj  <<<dim3(K1NB,PP),dim3(K1B),0,stream>>>(ea,perm,
              W(0,2),W(1,2),W(2,2),W(3,2),W(4,2),W(5,2),
              ep0,ep1,ep2,ep3,ep4,ep5,bpart);
  k_selfvec<<<dim3(1),dim3(1024),0,stream>>>(bpart,
              W(0,2),W(1,2),W(2,2),W(3,2),W(4,2),W(5,2),selfvec);

  dim3 gproj((NN+255)/256,PP), gagg((NN+63)/64,PP), gnode((NN+255)/256);

  // L0: e1 15->8, relu
  k_proj<15,8><<<gproj,b256,0,stream>>>(x,15,W(0,0),W(0,1),xl,xr);
  k_agg<8,8>  <<<gagg ,b256,0,stream>>>(xl,xr,off,srcs,ep0,W(0,3),selfvec+0*80,partial);
  k_final<8,true,false><<<gnode,b256,0,stream>>>(partial,W(0,4),hA);
  // L1: e2 8->8, relu
  k_proj<8,8> <<<gproj,b256,0,stream>>>(hA,16,W(1,0),W(1,1),xl,xr);
  k_agg<8,8>  <<<gagg ,b256,0,stream>>>(xl,xr,off,srcs,ep1,W(1,3),selfvec+1*80,partial);
  k_final<8,true,false><<<gnode,b256,0,stream>>>(partial,W(1,4),hB);
  // L2: e3 8->2, no relu
  k_proj<8,2> <<<gproj,b256,0,stream>>>(hB,16,W(2,0),W(2,1),xl,xr);
  k_agg<2,2>  <<<gagg ,b256,0,stream>>>(xl,xr,off,srcs,ep2,W(2,3),selfvec+2*80,partial);
  k_final<2,false,false><<<gnode,b256,0,stream>>>(partial,W(2,4),hA);
  // L3: d1 2->8, relu
  k_proj<2,8> <<<gproj,b256,0,stream>>>(hA,16,W(3,0),W(3,1),xl,xr);
  k_agg<8,8>  <<<gagg ,b256,0,stream>>>(xl,xr,off,srcs,ep3,W(3,3),selfvec+3*80,partial);
  k_final<8,true,false><<<gnode,b256,0,stream>>>(partial,W(3,4),hB);
  // L4: d2 8->8, relu
  k_proj<8,8> <<<gproj,b256,0,stream>>>(hB,16,W(4,0),W(4,1),xl,xr);
  k_agg<8,8>  <<<gagg ,b256,0,stream>>>(xl,xr,off,srcs,ep4,W(4,3),selfvec+4*80,partial);
  k_final<8,true,false><<<gnode,b256,0,stream>>>(partial,W(4,4),hA);
  // L5: d3 8->15, no relu -> d_out
  k_proj<8,15><<<gproj,b256,0,stream>>>(hA,16,W(5,0),W(5,1),xl,xr);
  k_agg<15,16><<<gagg ,b256,0,stream>>>(xl,xr,off,srcs,ep5,W(5,3),selfvec+5*80,partial);
  k_final<15,false,true><<<gnode,b256,0,stream>>>(partial,W(5,4),(float*)d_out);
}

// Round 2
// 1339.536 us; speedup vs baseline: 1.1441x; 1.1441x over previous
//
#include <hip/hip_runtime.h>
#include <stdint.h>

#define PP 5
#define EE 400000
#define NN 50000
#define PN (PP*NN)            // 250000 rows (protocol,node)
#define EPT (PP*EE)           // 2,000,000 edges total
#define SCAN_NB ((PN+1023)/1024)  // 245
#define G2 256                // eproj blocks per protocol
#define CHUNKS (EE/64)        // 6250 chunks of 64 edges

typedef unsigned int u32;
typedef unsigned short u16;
typedef float f32x4 __attribute__((ext_vector_type(4)));
typedef short s16x8 __attribute__((ext_vector_type(8)));
union FAB { s16x8 v; u32 w[4]; };

__device__ __forceinline__ u16 f2bf(float x){
  u32 u = __float_as_uint(x);
  u32 r = (u + 0x7fffu + ((u>>16)&1u))>>16;
  return (u16)r;
}
__device__ __forceinline__ u32 packbf(float a, float b){
  return (u32)f2bf(a) | ((u32)f2bf(b)<<16);
}
__device__ __forceinline__ float bf2f(u32 b){ return __uint_as_float(b<<16); }
__device__ __forceinline__ float lrelu(float x){ return fmaxf(x,0.f)+0.2f*fminf(x,0.f); }

// ---------------- utility ----------------
__global__ __launch_bounds__(256) void k_zero(u32* p, int n){
  int i=blockIdx.x*256+threadIdx.x; if(i<n) p[i]=0u;
}

// ---------------- CSR build ----------------
__global__ __launch_bounds__(256) void k_hist(const int* __restrict__ ei, u32* __restrict__ deg){
  int p=blockIdx.y, e=blockIdx.x*256+threadIdx.x;
  if(e<EE){
    int d = ei[(size_t)(p*2+1)*EE + e];
    atomicAdd(&deg[p*NN+d],1u);
  }
}

__global__ __launch_bounds__(256) void k_scan1(const u32* __restrict__ deg, u32* __restrict__ off, u32* __restrict__ bsum){
  __shared__ u32 s[256];
  int b=blockIdx.x, t=threadIdx.x;
  int base=b*1024+t*4;
  u32 v0=(base  <PN)?deg[base  ]:0u;
  u32 v1=(base+1<PN)?deg[base+1]:0u;
  u32 v2=(base+2<PN)?deg[base+2]:0u;
  u32 v3=(base+3<PN)?deg[base+3]:0u;
  u32 tot=v0+v1+v2+v3;
  s[t]=tot; __syncthreads();
  for(int o=1;o<256;o<<=1){
    u32 x=(t>=o)?s[t-o]:0u;
    __syncthreads();
    s[t]+=x;
    __syncthreads();
  }
  u32 excl=s[t]-tot;
  if(base  <PN) off[base  ]=excl;
  if(base+1<PN) off[base+1]=excl+v0;
  if(base+2<PN) off[base+2]=excl+v0+v1;
  if(base+3<PN) off[base+3]=excl+v0+v1+v2;
  if(t==255) bsum[b]=s[255];
}

__global__ __launch_bounds__(256) void k_scan2(const u32* __restrict__ bsum, u32* __restrict__ bsumX){
  __shared__ u32 s[256];
  int t=threadIdx.x;
  u32 v=(t<SCAN_NB)?bsum[t]:0u;
  s[t]=v; __syncthreads();
  for(int o=1;o<256;o<<=1){
    u32 x=(t>=o)?s[t-o]:0u;
    __syncthreads();
    s[t]+=x;
    __syncthreads();
  }
  if(t<SCAN_NB) bsumX[t]=s[t]-v;
}

__global__ __launch_bounds__(256) void k_scan3(u32* __restrict__ off, const u32* __restrict__ bsumX, u32* __restrict__ cursor){
  int i=blockIdx.x*256+threadIdx.x;
  if(i<PN){
    u32 v=off[i]+bsumX[i>>10];
    off[i]=v; cursor[i]=v;
  }
  if(i==0) off[PN]=(u32)EPT;
}

__global__ __launch_bounds__(256) void k_scatter(const int* __restrict__ ei, u32* __restrict__ cursor,
                                                 u32* __restrict__ srcs, u32* __restrict__ perm){
  int p=blockIdx.y, e=blockIdx.x*256+threadIdx.x;
  if(e<EE){
    int s = ei[(size_t)(p*2  )*EE + e];
    int d = ei[(size_t)(p*2+1)*EE + e];
    u32 pos = atomicAdd(&cursor[p*NN+d],1u);
    srcs[pos]=(u32)s;
    perm[(size_t)p*EE+e]=pos;
  }
}

// ---------------- edge-feature projection via MFMA (all 6 layers at once) ----------------
// D = Wcat^T (64 cols padded, bf16) x ea^T, 16x16x32 bf16 MFMA.
// weight-col layout m: e1:0..7, e2:8..15, e3:16..17, d1:24..31, d2:32..39, d3:48..62; rest pad=0.
__global__ __launch_bounds__(256) void k_eproj_mfma(
    const float* __restrict__ ea, const u32* __restrict__ perm,
    const float* __restrict__ we0, const float* __restrict__ we1,
    const float* __restrict__ we2, const float* __restrict__ we3,
    const float* __restrict__ we4, const float* __restrict__ we5,
    u16* __restrict__ ep0, u16* __restrict__ ep1, u16* __restrict__ ep2,
    u16* __restrict__ ep3, u16* __restrict__ ep4, u16* __restrict__ ep5,
    float* __restrict__ bpartP)
{
  __shared__ u16  sW[64*64];          // WcatT[m][k] bf16 (8 KB)
  __shared__ float sEA[64*44+16];     // 64 edge rows, pitch 44 floats, k=35..43 zeroed
  __shared__ u16  sEpi[4*16*72];      // per-wave 16 edges x 72 bf16 (pitch 144 B)
  __shared__ float sRed[64];

  const int t=threadIdx.x, p=blockIdx.y;
  const int w=t>>6, L=t&63, e16=L&15, quad=L>>4;

  for(int i=t;i<2048;i+=256) ((u32*)sW)[i]=0u;
  for(int i=t;i<64*44+16;i+=256) sEA[i]=0.f;
  if(t<64) sRed[t]=0.f;
  __syncthreads();

  #define FILLW(WPTR,FO,MOFF) { const float* wsrc=(WPTR)+(size_t)p*35*(FO); \
    for(int i=t;i<35*(FO);i+=256){ int k=i/(FO), f=i-k*(FO); \
      sW[((MOFF)+f)*64+k]=f2bf(wsrc[i]); } }
  FILLW(we0,8,0) FILLW(we1,8,8) FILLW(we2,2,16) FILLW(we3,8,24) FILLW(we4,8,32) FILLW(we5,15,48)
  #undef FILLW
  __syncthreads();

  // A fragments: A[m=lane&15 (+16*mt)][k=quad*8+j], held in regs for whole kernel
  FAB afr[4][2];
  #pragma unroll
  for(int mt=0;mt<4;mt++)
    #pragma unroll
    for(int kf=0;kf<2;kf++)
      afr[mt][kf].v = *(const s16x8*)&sW[(e16+16*mt)*64 + kf*32 + quad*8];

  float sumacc[16];
  #pragma unroll
  for(int i=0;i<16;i++) sumacc[i]=0.f;

  for(int c=blockIdx.x; c<CHUNKS; c+=G2){
    __syncthreads();
    // stage 64 edges (8960 B) coalesced -> sEA (pitch 44 floats)
    {
      const float* gsrc = ea + ((size_t)p*EE + (size_t)c*64)*35;
      for(int i=t;i<560;i+=256){
        f32x4 v = *(const f32x4*)(gsrc + i*4);
        int gw=i*4;
        #pragma unroll
        for(int j=0;j<4;j++){
          int wd=gw+j; int r=wd/35; int col=wd-r*35;
          sEA[r*44+col]=v[j];
        }
      }
    }
    __syncthreads();

    // B fragments for this wave's 16 edges
    const int rb=(w*16+e16)*44;
    f32x4 A0=*(const f32x4*)&sEA[rb+quad*8];
    f32x4 A1=*(const f32x4*)&sEA[rb+quad*8+4];
    f32x4 B0=*(const f32x4*)&sEA[rb+32];   // floats 32..35 (35==0)
    FAB fa, fb;
    fa.w[0]=packbf(A0.x,A0.y); fa.w[1]=packbf(A0.z,A0.w);
    fa.w[2]=packbf(A1.x,A1.y); fa.w[3]=packbf(A1.z,A1.w);
    const u32 msk=(quad==0)?0xffffffffu:0u;
    fb.w[0]=packbf(B0.x,B0.y)&msk; fb.w[1]=packbf(B0.z,B0.w)&msk;
    fb.w[2]=0u; fb.w[3]=0u;

    f32x4 acc0={0,0,0,0},acc1={0,0,0,0},acc2={0,0,0,0},acc3={0,0,0,0};
    acc0=__builtin_amdgcn_mfma_f32_16x16x32_bf16(afr[0][0].v, fa.v, acc0,0,0,0);
    acc0=__builtin_amdgcn_mfma_f32_16x16x32_bf16(afr[0][1].v, fb.v, acc0,0,0,0);
    acc1=__builtin_amdgcn_mfma_f32_16x16x32_bf16(afr[1][0].v, fa.v, acc1,0,0,0);
    acc1=__builtin_amdgcn_mfma_f32_16x16x32_bf16(afr[1][1].v, fb.v, acc1,0,0,0);
    acc2=__builtin_amdgcn_mfma_f32_16x16x32_bf16(afr[2][0].v, fa.v, acc2,0,0,0);
    acc2=__builtin_amdgcn_mfma_f32_16x16x32_bf16(afr[2][1].v, fb.v, acc2,0,0,0);
    acc3=__builtin_amdgcn_mfma_f32_16x16x32_bf16(afr[3][0].v, fa.v, acc3,0,0,0);
    acc3=__builtin_amdgcn_mfma_f32_16x16x32_bf16(afr[3][1].v, fb.v, acc3,0,0,0);

    #pragma unroll
    for(int r=0;r<4;r++){ sumacc[r]+=acc0[r]; sumacc[4+r]+=acc1[r]; sumacc[8+r]+=acc2[r]; sumacc[12+r]+=acc3[r]; }

    // epilogue: C layout col=lane&15 (edge), row=quad*4+reg (weight col) -> LDS transpose
    {
      u16* erow=&sEpi[w*1152 + e16*72];
      uint2 v;
      v.x=packbf(acc0[0],acc0[1]); v.y=packbf(acc0[2],acc0[3]);
      *(uint2*)(erow +  0 + 4*quad)=v;
      v.x=packbf(acc1[0],acc1[1]); v.y=packbf(acc1[2],acc1[3]);
      *(uint2*)(erow + 16 + 4*quad)=v;
      v.x=packbf(acc2[0],acc2[1]); v.y=packbf(acc2[2],acc2[3]);
      *(uint2*)(erow + 32 + 4*quad)=v;
      v.x=packbf(acc3[0],acc3[1]); v.y=packbf(acc3[2],acc3[3]);
      *(uint2*)(erow + 48 + 4*quad)=v;
    }
    __syncthreads();

    // scatter: 4 lanes per edge
    {
      const int e=L>>2, sub=L&3;
      const size_t gedge=(size_t)p*EE + (size_t)c*64 + w*16 + e;
      const u32 pos=perm[gedge];
      const u16* row=&sEpi[w*1152 + e*72];
      if(sub==0){
        ((uint4*)ep0)[pos]=*(const uint4*)(row+0);
        ((u32*)ep2)[pos]=*(const u32*)(row+16);
      } else if(sub==1){
        ((uint4*)ep1)[pos]=*(const uint4*)(row+8);
        ((uint4*)ep5)[(size_t)pos*2]=*(const uint4*)(row+48);
      } else if(sub==2){
        ((uint4*)ep3)[pos]=*(const uint4*)(row+24);
        ((uint4*)ep5)[(size_t)pos*2+1]=*(const uint4*)(row+56);
      } else {
        ((uint4*)ep4)[pos]=*(const uint4*)(row+32);
      }
    }
  }

  // column sums of fp32 projections (for self-loop mean vectors)
  #pragma unroll
  for(int i=0;i<16;i++){
    float v=sumacc[i];
    v+=__shfl_xor(v,1); v+=__shfl_xor(v,2); v+=__shfl_xor(v,4); v+=__shfl_xor(v,8);
    sumacc[i]=v;
  }
  if(e16==0){
    #pragma unroll
    for(int mt=0;mt<4;mt++)
      #pragma unroll
      for(int r=0;r<4;r++)
        atomicAdd(&sRed[16*mt+4*quad+r], sumacc[mt*4+r]);
  }
  __syncthreads();
  if(t<64) bpartP[((size_t)p*G2+blockIdx.x)*64+t]=sRed[t];
}

__global__ __launch_bounds__(320) void k_selfvec2(const float* __restrict__ bpartP, float* __restrict__ selfvec){
  int t=threadIdx.x;
  int p=t/64, m=t%64;
  float s=0.f;
  for(int b=0;b<G2;b++) s+=bpartP[((size_t)p*G2+b)*64+m];
  s*=(1.f/EE);
  int l=-1, f=0;
  if(m<8){l=0;f=m;} else if(m<16){l=1;f=m-8;} else if(m<18){l=2;f=m-16;}
  else if(m>=24&&m<32){l=3;f=m-24;} else if(m>=32&&m<40){l=4;f=m-32;}
  else if(m>=48&&m<63){l=5;f=m-48;}
  if(l>=0) selfvec[(size_t)(l*5+p)*16+f]=s;
}

// ---------------- per-layer node projection ----------------
template<int FI,int FO>
__global__ __launch_bounds__(256) void k_proj(
  const float* __restrict__ h, int hs,
  const float* __restrict__ wl, const float* __restrict__ wr,
  float* __restrict__ xl, float* __restrict__ xr)
{
  __shared__ float sl[FI*FO], sr[FI*FO];
  const int t=threadIdx.x, p=blockIdx.y;
  if(t<FI*FO){ sl[t]=wl[(size_t)p*FI*FO+t]; sr[t]=wr[(size_t)p*FI*FO+t]; }
  __syncthreads();
  const int n=blockIdx.x*256+t;
  if(n>=NN) return;
  float hv[FI];
  #pragma unroll
  for(int k=0;k<FI;k++) hv[k]=h[(size_t)n*hs+k];
  const size_t base=((size_t)p*NN+n)*16;
  #pragma unroll
  for(int f=0;f<FO;f++){
    float al=0.f, ar=0.f;
    #pragma unroll
    for(int k=0;k<FI;k++){ al+=hv[k]*sl[k*FO+f]; ar+=hv[k]*sr[k*FO+f]; }
    xl[base+f]=al; xr[base+f]=ar;
  }
}

template<int FO>
__device__ __forceinline__ void load_row(const float* __restrict__ g, float* arr){
  if constexpr(FO==2){
    float2 v=*(const float2*)g; arr[0]=v.x; arr[1]=v.y;
  } else {
    #pragma unroll
    for(int c=0;c<(FO+3)/4;c++){
      float4 v=((const float4*)g)[c];
      arr[4*c]=v.x;
      if(4*c+1<FO) arr[4*c+1]=v.y;
      if(4*c+2<FO) arr[4*c+2]=v.z;
      if(4*c+3<FO) arr[4*c+3]=v.w;
    }
  }
}

// ---------------- per-layer gather aggregation (4 lanes per row) ----------------
template<int FO,int EPAD>
__global__ __launch_bounds__(256) void k_agg(
  const float* __restrict__ xl, const float* __restrict__ xr,
  const u32* __restrict__ off, const u32* __restrict__ srcs,
  const u16* __restrict__ ep, const float* __restrict__ avec,
  const float* __restrict__ selfv, float* __restrict__ partial)
{
  const int t=threadIdx.x, p=blockIdx.y;
  const int n=blockIdx.x*64+(t>>2), sub=t&3;
  if(n>=NN) return;
  const int r=p*NN+n;
  float av[FO], xln[FO], xrn[FO];
  #pragma unroll
  for(int f=0;f<FO;f++) av[f]=avec[p*FO+f];
  load_row<FO>(xl+(size_t)r*16, xln);
  load_row<FO>(xr+(size_t)r*16, xrn);

  float den=0.f, num[FO];
  #pragma unroll
  for(int f=0;f<FO;f++) num[f]=0.f;
  if(sub==0){
    float e=0.f;
    #pragma unroll
    for(int f=0;f<FO;f++){ float m=xln[f]+xrn[f]+selfv[p*16+f]; e+=lrelu(m)*av[f]; }
    float ex=__expf(e);
    den=ex;
    #pragma unroll
    for(int f=0;f<FO;f++) num[f]=ex*xln[f];
  }
  const u32 j1=off[r+1];
  for(u32 j=off[r]+sub;j<j1;j+=4){
    const u32 s=srcs[j];
    float epv[FO];
    if constexpr(EPAD==8){
      uint4 q=*(const uint4*)(ep+(size_t)j*8);
      epv[0]=bf2f(q.x&0xffffu); epv[1]=bf2f(q.x>>16);
      epv[2]=bf2f(q.y&0xffffu); epv[3]=bf2f(q.y>>16);
      epv[4]=bf2f(q.z&0xffffu); epv[5]=bf2f(q.z>>16);
      epv[6]=bf2f(q.w&0xffffu); epv[7]=bf2f(q.w>>16);
    } else if constexpr(EPAD==2){
      u32 q=*(const u32*)(ep+(size_t)j*2);
      epv[0]=bf2f(q&0xffffu); epv[1]=bf2f(q>>16);
    } else {
      const uint4* qq=(const uint4*)(ep+(size_t)j*16);
      uint4 q0=qq[0], q1=qq[1];
      u32 w[8]={q0.x,q0.y,q0.z,q0.w,q1.x,q1.y,q1.z,q1.w};
      #pragma unroll
      for(int i=0;i<8;i++){
        if(2*i  <FO) epv[2*i  ]=bf2f(w[i]&0xffffu);
        if(2*i+1<FO) epv[2*i+1]=bf2f(w[i]>>16);
      }
    }
    float xls[FO];
    load_row<FO>(xl+((size_t)p*NN+s)*16, xls);
    float e=0.f;
    #pragma unroll
    for(int f=0;f<FO;f++){ float m=xls[f]+xrn[f]+epv[f]; e+=lrelu(m)*av[f]; }
    const float ex=__expf(e);
    den+=ex;
    #pragma unroll
    for(int f=0;f<FO;f++) num[f]+=ex*xls[f];
  }
  den+=__shfl_xor(den,1); den+=__shfl_xor(den,2);
  #pragma unroll
  for(int f=0;f<FO;f++){ num[f]+=__shfl_xor(num[f],1); num[f]+=__shfl_xor(num[f],2); }
  if(sub==0){
    const float inv=1.f/den;
    float* dst=partial+(size_t)r*16;
    #pragma unroll
    for(int f=0;f<FO;f++) dst[f]=num[f]*inv;
  }
}

// ---------------- combine protocols + bias + activation ----------------
template<int FO,bool RELU,bool OUT15>
__global__ __launch_bounds__(256) void k_final(
  const float* __restrict__ partial, const float* __restrict__ b,
  float* __restrict__ hout)
{
  const int n=blockIdx.x*256+threadIdx.x;
  if(n>=NN) return;
  float s[FO];
  #pragma unroll
  for(int f=0;f<FO;f++) s[f]=0.f;
  #pragma unroll
  for(int p=0;p<PP;p++){
    const float* src=partial+((size_t)p*NN+n)*16;
    #pragma unroll
    for(int f=0;f<FO;f++) s[f]+=src[f];
  }
  #pragma unroll
  for(int p=0;p<PP;p++){
    #pragma unroll
    for(int f=0;f<FO;f++) s[f]+=b[p*FO+f];
  }
  #pragma unroll
  for(int f=0;f<FO;f++){
    float v=RELU?fmaxf(s[f],0.f):s[f];
    hout[(size_t)n*(OUT15?15:16)+f]=v;
  }
}

// ---------------- launch ----------------
extern "C" void kernel_launch(void* const* d_in, const int* in_sizes, int n_in,
                              void* d_out, int out_size, void* d_ws, size_t ws_size,
                              hipStream_t stream)
{
  const float* x =(const float*)d_in[0];
  const float* ea=(const float*)d_in[1];
  const int*   ei=(const int*)d_in[2];
  auto W=[&](int l,int k)->const float*{ return (const float*)d_in[3+5*l+k]; };

  char* base=(char*)d_ws; size_t cur=0;
  auto alloc=[&](size_t bytes)->char*{ char* pp=base+cur; cur=(cur+bytes+255)&~(size_t)255; return pp; };
  u32*  deg    =(u32*) alloc((size_t)PN*4);
  u32*  off    =(u32*) alloc((size_t)(PN+1)*4);
  u32*  cursor =(u32*) alloc((size_t)PN*4);
  u32*  bsum   =(u32*) alloc(256*4);
  u32*  bsumX  =(u32*) alloc(256*4);
  u32*  srcs   =(u32*) alloc((size_t)EPT*4);
  u32*  perm   =(u32*) alloc((size_t)EPT*4);
  float* bpartP=(float*)alloc((size_t)PP*G2*64*4);
  float* selfvec=(float*)alloc(6*PP*16*4);
  float* xl    =(float*)alloc((size_t)PN*16*4);
  float* xr    =(float*)alloc((size_t)PN*16*4);
  float* partial=(float*)alloc((size_t)PN*16*4);
  float* hA    =(float*)alloc((size_t)NN*16*4);
  float* hB    =(float*)alloc((size_t)NN*16*4);
  u16*  ep0    =(u16*) alloc((size_t)EPT*8*2);
  u16*  ep1    =(u16*) alloc((size_t)EPT*8*2);
  u16*  ep2    =(u16*) alloc((size_t)EPT*2*2);
  u16*  ep3    =(u16*) alloc((size_t)EPT*8*2);
  u16*  ep4    =(u16*) alloc((size_t)EPT*8*2);
  u16*  ep5    =(u16*) alloc((size_t)EPT*16*2);
  (void)ws_size; (void)in_sizes; (void)n_in; (void)out_size;

  dim3 b256(256);
  k_zero   <<<dim3((PN+255)/256),b256,0,stream>>>(deg,PN);
  k_hist   <<<dim3((EE+255)/256,PP),b256,0,stream>>>(ei,deg);
  k_scan1  <<<dim3(SCAN_NB),b256,0,stream>>>(deg,off,bsum);
  k_scan2  <<<dim3(1),b256,0,stream>>>(bsum,bsumX);
  k_scan3  <<<dim3((PN+255)/256),b256,0,stream>>>(off,bsumX,cursor);
  k_scatter<<<dim3((EE+255)/256,PP),b256,0,stream>>>(ei,cursor,srcs,perm);
  k_eproj_mfma<<<dim3(G2,PP),b256,0,stream>>>(ea,perm,
              W(0,2),W(1,2),W(2,2),W(3,2),W(4,2),W(5,2),
              ep0,ep1,ep2,ep3,ep4,ep5,bpartP);
  k_selfvec2<<<dim3(1),dim3(320),0,stream>>>(bpartP,selfvec);

  dim3 gproj((NN+255)/256,PP), gagg((NN+63)/64,PP), gnode((NN+255)/256);

  // L0: e1 15->8, relu
  k_proj<15,8><<<gproj,b256,0,stream>>>(x,15,W(0,0),W(0,1),xl,xr);
  k_agg<8,8>  <<<gagg ,b256,0,stream>>>(xl,xr,off,srcs,ep0,W(0,3),selfvec+0*80,partial);
  k_final<8,true,false><<<gnode,b256,0,stream>>>(partial,W(0,4),hA);
  // L1: e2 8->8, relu
  k_proj<8,8> <<<gproj,b256,0,stream>>>(hA,16,W(1,0),W(1,1),xl,xr);
  k_agg<8,8>  <<<gagg ,b256,0,stream>>>(xl,xr,off,srcs,ep1,W(1,3),selfvec+1*80,partial);
  k_final<8,true,false><<<gnode,b256,0,stream>>>(partial,W(1,4),hB);
  // L2: e3 8->2, no relu
  k_proj<8,2> <<<gproj,b256,0,stream>>>(hB,16,W(2,0),W(2,1),xl,xr);
  k_agg<2,2>  <<<gagg ,b256,0,stream>>>(xl,xr,off,srcs,ep2,W(2,3),selfvec+2*80,partial);
  k_final<2,false,false><<<gnode,b256,0,stream>>>(partial,W(2,4),hA);
  // L3: d1 2->8, relu
  k_proj<2,8> <<<gproj,b256,0,stream>>>(hA,16,W(3,0),W(3,1),xl,xr);
  k_agg<8,8>  <<<gagg ,b256,0,stream>>>(xl,xr,off,srcs,ep3,W(3,3),selfvec+3*80,partial);
  k_final<8,true,false><<<gnode,b256,0,stream>>>(partial,W(3,4),hB);
  // L4: d2 8->8, relu
  k_proj<8,8> <<<gproj,b256,0,stream>>>(hB,16,W(4,0),W(4,1),xl,xr);
  k_agg<8,8>  <<<gagg ,b256,0,stream>>>(xl,xr,off,srcs,ep4,W(4,3),selfvec+4*80,partial);
  k_final<8,true,false><<<gnode,b256,0,stream>>>(partial,W(4,4),hA);
  // L5: d3 8->15, no relu -> d_out
  k_proj<8,15><<<gproj,b256,0,stream>>>(hA,16,W(5,0),W(5,1),xl,xr);
  k_agg<15,16><<<gagg ,b256,0,stream>>>(xl,xr,off,srcs,ep5,W(5,3),selfvec+5*80,partial);
  k_final<15,false,true><<<gnode,b256,0,stream>>>(partial,W(5,4),(float*)d_out);
}

// Round 4
// 1012.116 us; speedup vs baseline: 1.5142x; 1.3235x over previous
//
#include <hip/hip_runtime.h>
#include <stdint.h>

#define PP 5
#define EE 400000
#define NN 50000
#define PN (PP*NN)            // 250000 rows (protocol,node)
#define EPT (PP*EE)           // 2,000,000 edges total
#define SCAN_NB ((PN+1023)/1024)  // 245
#define G2 256                // eproj blocks per protocol
#define NGRP (EE/64)          // 6250 groups of 64 slots per protocol

typedef unsigned int u32;
typedef unsigned short u16;
typedef float f32x4 __attribute__((ext_vector_type(4)));
typedef short s16x8 __attribute__((ext_vector_type(8)));
union FAB { s16x8 v; u32 w[4]; };

__device__ __forceinline__ u16 f2bf(float x){
  u32 u = __float_as_uint(x);
  u32 r = (u + 0x7fffu + ((u>>16)&1u))>>16;
  return (u16)r;
}
__device__ __forceinline__ u32 packbf(float a, float b){
  return (u32)f2bf(a) | ((u32)f2bf(b)<<16);
}
__device__ __forceinline__ float bf2f(u32 b){ return __uint_as_float(b<<16); }
__device__ __forceinline__ float lrelu(float x){ return fmaxf(x,0.f)+0.2f*fminf(x,0.f); }

// ---------------- utility ----------------
__global__ __launch_bounds__(256) void k_zero(u32* p, int n){
  int i=blockIdx.x*256+threadIdx.x; if(i<n) p[i]=0u;
}

// ---------------- CSR build ----------------
__global__ __launch_bounds__(256) void k_hist(const int* __restrict__ ei, u32* __restrict__ deg){
  int p=blockIdx.y, e=blockIdx.x*256+threadIdx.x;
  if(e<EE){
    int d = ei[(size_t)(p*2+1)*EE + e];
    atomicAdd(&deg[p*NN+d],1u);
  }
}

__global__ __launch_bounds__(256) void k_scan1(const u32* __restrict__ deg, u32* __restrict__ off, u32* __restrict__ bsum){
  __shared__ u32 s[256];
  int b=blockIdx.x, t=threadIdx.x;
  int base=b*1024+t*4;
  u32 v0=(base  <PN)?deg[base  ]:0u;
  u32 v1=(base+1<PN)?deg[base+1]:0u;
  u32 v2=(base+2<PN)?deg[base+2]:0u;
  u32 v3=(base+3<PN)?deg[base+3]:0u;
  u32 tot=v0+v1+v2+v3;
  s[t]=tot; __syncthreads();
  for(int o=1;o<256;o<<=1){
    u32 x=(t>=o)?s[t-o]:0u;
    __syncthreads();
    s[t]+=x;
    __syncthreads();
  }
  u32 excl=s[t]-tot;
  if(base  <PN) off[base  ]=excl;
  if(base+1<PN) off[base+1]=excl+v0;
  if(base+2<PN) off[base+2]=excl+v0+v1;
  if(base+3<PN) off[base+3]=excl+v0+v1+v2;
  if(t==255) bsum[b]=s[255];
}

__global__ __launch_bounds__(256) void k_scan2(const u32* __restrict__ bsum, u32* __restrict__ bsumX){
  __shared__ u32 s[256];
  int t=threadIdx.x;
  u32 v=(t<SCAN_NB)?bsum[t]:0u;
  s[t]=v; __syncthreads();
  for(int o=1;o<256;o<<=1){
    u32 x=(t>=o)?s[t-o]:0u;
    __syncthreads();
    s[t]+=x;
    __syncthreads();
  }
  if(t<SCAN_NB) bsumX[t]=s[t]-v;
}

__global__ __launch_bounds__(256) void k_scan3(u32* __restrict__ off, const u32* __restrict__ bsumX, u32* __restrict__ cursor){
  int i=blockIdx.x*256+threadIdx.x;
  if(i<PN){
    u32 v=off[i]+bsumX[i>>10];
    off[i]=v; cursor[i]=v;
  }
  if(i==0) off[PN]=(u32)EPT;
}

__global__ __launch_bounds__(256) void k_scatter(const int* __restrict__ ei, u32* __restrict__ cursor,
                                                 u32* __restrict__ srcs, u32* __restrict__ eid){
  int p=blockIdx.y, e=blockIdx.x*256+threadIdx.x;
  if(e<EE){
    int s = ei[(size_t)(p*2  )*EE + e];
    int d = ei[(size_t)(p*2+1)*EE + e];
    u32 pos = atomicAdd(&cursor[p*NN+d],1u);
    srcs[pos]=(u32)s;
    eid[pos]=(u32)e;
  }
}

// ---------------- edge-feature projection via MFMA, CSR-slot order ----------------
__global__ __launch_bounds__(256) void k_eproj_mfma(
    const float* __restrict__ ea, const u32* __restrict__ eid,
    const float* __restrict__ we0, const float* __restrict__ we1,
    const float* __restrict__ we2, const float* __restrict__ we3,
    const float* __restrict__ we4, const float* __restrict__ we5,
    u16* __restrict__ ep0, u16* __restrict__ ep1, u16* __restrict__ ep2,
    u16* __restrict__ ep3, u16* __restrict__ ep4, u16* __restrict__ ep5,
    float* __restrict__ bpartP)
{
  __shared__ u16  sW[64*64];          // WcatT[m][k] bf16 (8 KB)
  __shared__ u16  sEpi[4*16*72];      // per-wave 16 edges x 72 bf16
  __shared__ float sRed[64];

  const int t=threadIdx.x, p=blockIdx.y;
  const int w=t>>6, L=t&63, e16=L&15, quad=L>>4;

  for(int i=t;i<2048;i+=256) ((u32*)sW)[i]=0u;
  if(t<64) sRed[t]=0.f;
  __syncthreads();

  #define FILLW(WPTR,FO,MOFF) { const float* wsrc=(WPTR)+(size_t)p*35*(FO); \
    for(int i=t;i<35*(FO);i+=256){ int k=i/(FO), f=i-k*(FO); \
      sW[((MOFF)+f)*64+k]=f2bf(wsrc[i]); } }
  FILLW(we0,8,0) FILLW(we1,8,8) FILLW(we2,2,16) FILLW(we3,8,24) FILLW(we4,8,32) FILLW(we5,15,48)
  #undef FILLW
  __syncthreads();

  // A fragments: A[m=lane&15 (+16*mt)][k=quad*8+j], held in regs for whole kernel
  FAB afr[4][2];
  #pragma unroll
  for(int mt=0;mt<4;mt++)
    #pragma unroll
    for(int kf=0;kf<2;kf++)
      afr[mt][kf].v = *(const s16x8*)&sW[(e16+16*mt)*64 + kf*32 + quad*8];

  float sumacc[16];
  #pragma unroll
  for(int i=0;i<16;i++) sumacc[i]=0.f;

  u16* const myEpi = &sEpi[w*1152];   // this wave's 16x72 region

  for(int g=blockIdx.x; g<NGRP; g+=G2){
    const size_t jbase = (size_t)p*EE + (size_t)g*64 + w*16;

    // gather this lane's edge row segment straight to registers
    const u32 eedge = eid[jbase + e16];
    const float* row = ea + ((size_t)p*EE + eedge)*35;
    float v0=row[quad*8+0], v1=row[quad*8+1], v2=row[quad*8+2], v3=row[quad*8+3];
    float v4=row[quad*8+4], v5=row[quad*8+5], v6=row[quad*8+6], v7=row[quad*8+7];
    float b0=0.f,b1=0.f,b2=0.f;
    if(quad==0){ b0=row[32]; b1=row[33]; b2=row[34]; }

    FAB fa, fb;
    fa.w[0]=packbf(v0,v1); fa.w[1]=packbf(v2,v3);
    fa.w[2]=packbf(v4,v5); fa.w[3]=packbf(v6,v7);
    fb.w[0]=packbf(b0,b1); fb.w[1]=packbf(b2,0.f);
    fb.w[2]=0u; fb.w[3]=0u;

    f32x4 acc0={0,0,0,0},acc1={0,0,0,0},acc2={0,0,0,0},acc3={0,0,0,0};
    acc0=__builtin_amdgcn_mfma_f32_16x16x32_bf16(afr[0][0].v, fa.v, acc0,0,0,0);
    acc0=__builtin_amdgcn_mfma_f32_16x16x32_bf16(afr[0][1].v, fb.v, acc0,0,0,0);
    acc1=__builtin_amdgcn_mfma_f32_16x16x32_bf16(afr[1][0].v, fa.v, acc1,0,0,0);
    acc1=__builtin_amdgcn_mfma_f32_16x16x32_bf16(afr[1][1].v, fb.v, acc1,0,0,0);
    acc2=__builtin_amdgcn_mfma_f32_16x16x32_bf16(afr[2][0].v, fa.v, acc2,0,0,0);
    acc2=__builtin_amdgcn_mfma_f32_16x16x32_bf16(afr[2][1].v, fb.v, acc2,0,0,0);
    acc3=__builtin_amdgcn_mfma_f32_16x16x32_bf16(afr[3][0].v, fa.v, acc3,0,0,0);
    acc3=__builtin_amdgcn_mfma_f32_16x16x32_bf16(afr[3][1].v, fb.v, acc3,0,0,0);

    #pragma unroll
    for(int r=0;r<4;r++){ sumacc[r]+=acc0[r]; sumacc[4+r]+=acc1[r]; sumacc[8+r]+=acc2[r]; sumacc[12+r]+=acc3[r]; }

    // epilogue: C layout col=lane&15 (edge), row=quad*4+reg (weight col m) -> per-wave LDS transpose
    {
      u16* erow=&myEpi[e16*72];
      uint2 q;
      q.x=packbf(acc0[0],acc0[1]); q.y=packbf(acc0[2],acc0[3]);
      *(uint2*)(erow +  0 + 4*quad)=q;
      q.x=packbf(acc1[0],acc1[1]); q.y=packbf(acc1[2],acc1[3]);
      *(uint2*)(erow + 16 + 4*quad)=q;
      q.x=packbf(acc2[0],acc2[1]); q.y=packbf(acc2[2],acc2[3]);
      *(uint2*)(erow + 32 + 4*quad)=q;
      q.x=packbf(acc3[0],acc3[1]); q.y=packbf(acc3[2],acc3[3]);
      *(uint2*)(erow + 48 + 4*quad)=q;
    }
    __builtin_amdgcn_s_waitcnt(0);  // wave-internal LDS write->read ordering

    // coalesced stores (contiguous slot ranges per array)
    {
      const int grp=L>>4, e=L&15;
      const u16* erow=&myEpi[e*72];
      if(grp==0)      ((uint4*)ep0)[jbase+e]=*(const uint4*)(erow+ 0);
      else if(grp==1) ((uint4*)ep1)[jbase+e]=*(const uint4*)(erow+ 8);
      else if(grp==2) ((uint4*)ep3)[jbase+e]=*(const uint4*)(erow+24);
      else            ((uint4*)ep4)[jbase+e]=*(const uint4*)(erow+32);
      if(L<32){
        const int e2=L>>1, half=L&1;
        ((uint4*)ep5)[(jbase+e2)*2+half]=*(const uint4*)(&myEpi[e2*72]+48+8*half);
      } else if(L<48){
        const int e2=L-32;
        ((u32*)ep2)[jbase+e2]=*(const u32*)(&myEpi[e2*72]+16);
      }
    }
  }

  // column sums of fp32 projections (for self-loop mean vectors)
  #pragma unroll
  for(int i=0;i<16;i++){
    float v=sumacc[i];
    v+=__shfl_xor(v,1); v+=__shfl_xor(v,2); v+=__shfl_xor(v,4); v+=__shfl_xor(v,8);
    sumacc[i]=v;
  }
  if(e16==0){
    #pragma unroll
    for(int mt=0;mt<4;mt++)
      #pragma unroll
      for(int r=0;r<4;r++)
        atomicAdd(&sRed[16*mt+4*quad+r], sumacc[mt*4+r]);
  }
  __syncthreads();
  if(t<64) bpartP[((size_t)p*G2+blockIdx.x)*64+t]=sRed[t];
}

__global__ __launch_bounds__(320) void k_selfvec2(const float* __restrict__ bpartP, float* __restrict__ selfvec){
  int t=threadIdx.x;
  int p=t/64, m=t%64;
  float s=0.f;
  for(int b=0;b<G2;b++) s+=bpartP[((size_t)p*G2+b)*64+m];
  s*=(1.f/EE);
  int l=-1, f=0;
  if(m<8){l=0;f=m;} else if(m<16){l=1;f=m-8;} else if(m<18){l=2;f=m-16;}
  else if(m>=24&&m<32){l=3;f=m-24;} else if(m>=32&&m<40){l=4;f=m-32;}
  else if(m>=48&&m<63){l=5;f=m-48;}
  if(l>=0) selfvec[(size_t)(l*5+p)*16+f]=s;
}

// ---------------- first-layer node projection ----------------
template<int FI,int FO>
__global__ __launch_bounds__(256) void k_proj(
  const float* __restrict__ h, int hs,
  const float* __restrict__ wl, const float* __restrict__ wr,
  float* __restrict__ xl, float* __restrict__ xr)
{
  __shared__ float sl[FI*FO], sr[FI*FO];
  const int t=threadIdx.x, p=blockIdx.y;
  if(t<FI*FO){ sl[t]=wl[(size_t)p*FI*FO+t]; sr[t]=wr[(size_t)p*FI*FO+t]; }
  __syncthreads();
  const int n=blockIdx.x*256+t;
  if(n>=NN) return;
  float hv[FI];
  #pragma unroll
  for(int k=0;k<FI;k++) hv[k]=h[(size_t)n*hs+k];
  const size_t base=((size_t)p*NN+n)*FO;
  #pragma unroll
  for(int f=0;f<FO;f++){
    float al=0.f, ar=0.f;
    #pragma unroll
    for(int k=0;k<FI;k++){ al+=hv[k]*sl[k*FO+f]; ar+=hv[k]*sr[k*FO+f]; }
    xl[base+f]=al; xr[base+f]=ar;
  }
}

// ---------------- fused combine(prev layer) + projection(next layer) ----------------
// PO = output pitch of xl/xr (>= FO); pad lanes zeroed.
template<int FI,int FO,int PO,bool RELU>
__global__ __launch_bounds__(256) void k_comb(
  const float* __restrict__ partial, const float* __restrict__ b,
  const float* __restrict__ wl, const float* __restrict__ wr,
  float* __restrict__ xl, float* __restrict__ xr)
{
  __shared__ float sl[5*FI*FO], sr[5*FI*FO], sbias[FI];
  const int t=threadIdx.x;
  for(int i=t;i<5*FI*FO;i+=256){ sl[i]=wl[i]; sr[i]=wr[i]; }
  if(t<FI){ float s=0.f; for(int p=0;p<PP;p++) s+=b[p*FI+t]; sbias[t]=s; }
  __syncthreads();
  const int n=blockIdx.x*256+t;
  if(n>=NN) return;
  float h[FI];
  #pragma unroll
  for(int f=0;f<FI;f++) h[f]=sbias[f];
  #pragma unroll
  for(int p=0;p<PP;p++){
    const float* src=partial+((size_t)p*NN+n)*FI;
    #pragma unroll
    for(int f=0;f<FI;f++) h[f]+=src[f];
  }
  if(RELU){
    #pragma unroll
    for(int f=0;f<FI;f++) h[f]=fmaxf(h[f],0.f);
  }
  #pragma unroll
  for(int p=0;p<PP;p++){
    const float* wlp=&sl[p*FI*FO];
    const float* wrp=&sr[p*FI*FO];
    const size_t base=((size_t)p*NN+n)*PO;
    #pragma unroll
    for(int f=0;f<FO;f++){
      float al=0.f, ar=0.f;
      #pragma unroll
      for(int k=0;k<FI;k++){ al+=h[k]*wlp[k*FO+f]; ar+=h[k]*wrp[k*FO+f]; }
      xl[base+f]=al; xr[base+f]=ar;
    }
    #pragma unroll
    for(int f=FO;f<PO;f++){ xl[base+f]=0.f; xr[base+f]=0.f; }
  }
}

template<int FO,int PO>
__device__ __forceinline__ void load_row(const float* __restrict__ g, float* arr){
  if constexpr(FO==2){
    float2 v=*(const float2*)g; arr[0]=v.x; arr[1]=v.y;
  } else {
    #pragma unroll
    for(int c=0;c<(FO+3)/4;c++){
      float4 v=((const float4*)g)[c];
      arr[4*c]=v.x;
      if(4*c+1<FO) arr[4*c+1]=v.y;
      if(4*c+2<FO) arr[4*c+2]=v.z;
      if(4*c+3<FO) arr[4*c+3]=v.w;
    }
  }
}

// ---------------- per-layer gather aggregation (4 lanes per row) ----------------
template<int FO,int EPAD,int PO>
__global__ __launch_bounds__(256) void k_agg(
  const float* __restrict__ xl, const float* __restrict__ xr,
  const u32* __restrict__ off, const u32* __restrict__ srcs,
  const u16* __restrict__ ep, const float* __restrict__ avec,
  const float* __restrict__ selfv, float* __restrict__ partial)
{
  const int t=threadIdx.x, p=blockIdx.y;
  const int n=blockIdx.x*64+(t>>2), sub=t&3;
  if(n>=NN) return;
  const int r=p*NN+n;
  float av[FO], xln[FO], xrn[FO];
  #pragma unroll
  for(int f=0;f<FO;f++) av[f]=avec[p*FO+f];
  load_row<FO,PO>(xl+(size_t)r*PO, xln);
  load_row<FO,PO>(xr+(size_t)r*PO, xrn);

  float den=0.f, num[FO];
  #pragma unroll
  for(int f=0;f<FO;f++) num[f]=0.f;
  if(sub==0){
    float e=0.f;
    #pragma unroll
    for(int f=0;f<FO;f++){ float m=xln[f]+xrn[f]+selfv[p*16+f]; e+=lrelu(m)*av[f]; }
    float ex=__expf(e);
    den=ex;
    #pragma unroll
    for(int f=0;f<FO;f++) num[f]=ex*xln[f];
  }
  const u32 j1=off[r+1];
  for(u32 j=off[r]+sub;j<j1;j+=4){
    const u32 s=srcs[j];
    float epv[FO];
    if constexpr(EPAD==8){
      uint4 q=*(const uint4*)(ep+(size_t)j*8);
      epv[0]=bf2f(q.x&0xffffu); epv[1]=bf2f(q.x>>16);
      epv[2]=bf2f(q.y&0xffffu); epv[3]=bf2f(q.y>>16);
      epv[4]=bf2f(q.z&0xffffu); epv[5]=bf2f(q.z>>16);
      epv[6]=bf2f(q.w&0xffffu); epv[7]=bf2f(q.w>>16);
    } else if constexpr(EPAD==2){
      u32 q=*(const u32*)(ep+(size_t)j*2);
      epv[0]=bf2f(q&0xffffu); epv[1]=bf2f(q>>16);
    } else {
      const uint4* qq=(const uint4*)(ep+(size_t)j*16);
      uint4 q0=qq[0], q1=qq[1];
      u32 w[8]={q0.x,q0.y,q0.z,q0.w,q1.x,q1.y,q1.z,q1.w};
      #pragma unroll
      for(int i=0;i<8;i++){
        if(2*i  <FO) epv[2*i  ]=bf2f(w[i]&0xffffu);
        if(2*i+1<FO) epv[2*i+1]=bf2f(w[i]>>16);
      }
    }
    float xls[FO];
    load_row<FO,PO>(xl+((size_t)p*NN+s)*PO, xls);
    float e=0.f;
    #pragma unroll
    for(int f=0;f<FO;f++){ float m=xls[f]+xrn[f]+epv[f]; e+=lrelu(m)*av[f]; }
    const float ex=__expf(e);
    den+=ex;
    #pragma unroll
    for(int f=0;f<FO;f++) num[f]+=ex*xls[f];
  }
  den+=__shfl_xor(den,1); den+=__shfl_xor(den,2);
  #pragma unroll
  for(int f=0;f<FO;f++){ num[f]+=__shfl_xor(num[f],1); num[f]+=__shfl_xor(num[f],2); }
  if(sub==0){
    const float inv=1.f/den;
    float* dst=partial+(size_t)r*PO;
    #pragma unroll
    for(int f=0;f<FO;f++) dst[f]=num[f]*inv;
  }
}

// ---------------- final combine (d3 output, 15 wide, no relu) ----------------
__global__ __launch_bounds__(256) void k_final15(
  const float* __restrict__ partial, const float* __restrict__ b,
  float* __restrict__ out)
{
  __shared__ float sbias[15];
  const int t=threadIdx.x;
  if(t<15){ float s=0.f; for(int p=0;p<PP;p++) s+=b[p*15+t]; sbias[t]=s; }
  __syncthreads();
  const int n=blockIdx.x*256+t;
  if(n>=NN) return;
  float s[15];
  #pragma unroll
  for(int f=0;f<15;f++) s[f]=sbias[f];
  #pragma unroll
  for(int p=0;p<PP;p++){
    const float* src=partial+((size_t)p*NN+n)*16;
    #pragma unroll
    for(int f=0;f<15;f++) s[f]+=src[f];
  }
  #pragma unroll
  for(int f=0;f<15;f++) out[(size_t)n*15+f]=s[f];
}

// ---------------- launch ----------------
extern "C" void kernel_launch(void* const* d_in, const int* in_sizes, int n_in,
                              void* d_out, int out_size, void* d_ws, size_t ws_size,
                              hipStream_t stream)
{
  const float* x =(const float*)d_in[0];
  const float* ea=(const float*)d_in[1];
  const int*   ei=(const int*)d_in[2];
  auto W=[&](int l,int k)->const float*{ return (const float*)d_in[3+5*l+k]; };

  char* base=(char*)d_ws; size_t cur=0;
  auto alloc=[&](size_t bytes)->char*{ char* pp=base+cur; cur=(cur+bytes+255)&~(size_t)255; return pp; };
  u32*  deg    =(u32*) alloc((size_t)PN*4);
  u32*  off    =(u32*) alloc((size_t)(PN+1)*4);
  u32*  cursor =(u32*) alloc((size_t)PN*4);
  u32*  bsum   =(u32*) alloc(256*4);
  u32*  bsumX  =(u32*) alloc(256*4);
  u32*  srcs   =(u32*) alloc((size_t)EPT*4);
  u32*  eid    =(u32*) alloc((size_t)EPT*4);
  float* bpartP=(float*)alloc((size_t)PP*G2*64*4);
  float* selfvec=(float*)alloc(6*PP*16*4);
  float* xl    =(float*)alloc((size_t)PN*16*4);
  float* xr    =(float*)alloc((size_t)PN*16*4);
  float* partial=(float*)alloc((size_t)PN*16*4);
  u16*  ep0    =(u16*) alloc((size_t)EPT*8*2);
  u16*  ep1    =(u16*) alloc((size_t)EPT*8*2);
  u16*  ep2    =(u16*) alloc((size_t)EPT*2*2);
  u16*  ep3    =(u16*) alloc((size_t)EPT*8*2);
  u16*  ep4    =(u16*) alloc((size_t)EPT*8*2);
  u16*  ep5    =(u16*) alloc((size_t)EPT*16*2);
  (void)ws_size; (void)in_sizes; (void)n_in; (void)out_size;

  dim3 b256(256);
  k_zero   <<<dim3((PN+255)/256),b256,0,stream>>>(deg,PN);
  k_hist   <<<dim3((EE+255)/256,PP),b256,0,stream>>>(ei,deg);
  k_scan1  <<<dim3(SCAN_NB),b256,0,stream>>>(deg,off,bsum);
  k_scan2  <<<dim3(1),b256,0,stream>>>(bsum,bsumX);
  k_scan3  <<<dim3((PN+255)/256),b256,0,stream>>>(off,bsumX,cursor);
  k_scatter<<<dim3((EE+255)/256,PP),b256,0,stream>>>(ei,cursor,srcs,eid);
  k_eproj_mfma<<<dim3(G2,PP),b256,0,stream>>>(ea,eid,
              W(0,2),W(1,2),W(2,2),W(3,2),W(4,2),W(5,2),
              ep0,ep1,ep2,ep3,ep4,ep5,bpartP);
  k_selfvec2<<<dim3(1),dim3(320),0,stream>>>(bpartP,selfvec);

  dim3 gproj((NN+255)/256,PP), gagg((NN+63)/64,PP), gnode((NN+255)/256);

  // L0: e1 15->8
  k_proj<15,8><<<gproj,b256,0,stream>>>(x,15,W(0,0),W(0,1),xl,xr);
  k_agg<8,8,8>   <<<gagg ,b256,0,stream>>>(xl,xr,off,srcs,ep0,W(0,3),selfvec+0*80,partial);
  k_comb<8,8,8,true><<<gnode,b256,0,stream>>>(partial,W(0,4),W(1,0),W(1,1),xl,xr);   // relu(e1) -> proj e2
  k_agg<8,8,8>   <<<gagg ,b256,0,stream>>>(xl,xr,off,srcs,ep1,W(1,3),selfvec+1*80,partial);
  k_comb<8,2,2,true><<<gnode,b256,0,stream>>>(partial,W(1,4),W(2,0),W(2,1),xl,xr);   // relu(e2) -> proj e3
  k_agg<2,2,2>   <<<gagg ,b256,0,stream>>>(xl,xr,off,srcs,ep2,W(2,3),selfvec+2*80,partial);
  k_comb<2,8,8,false><<<gnode,b256,0,stream>>>(partial,W(2,4),W(3,0),W(3,1),xl,xr);  // NO relu after e3 -> proj d1
  k_agg<8,8,8>   <<<gagg ,b256,0,stream>>>(xl,xr,off,srcs,ep3,W(3,3),selfvec+3*80,partial);
  k_comb<8,8,8,true><<<gnode,b256,0,stream>>>(partial,W(3,4),W(4,0),W(4,1),xl,xr);   // relu(d1) -> proj d2
  k_agg<8,8,8>   <<<gagg ,b256,0,stream>>>(xl,xr,off,srcs,ep4,W(4,3),selfvec+4*80,partial);
  k_comb<8,15,16,true><<<gnode,b256,0,stream>>>(partial,W(4,4),W(5,0),W(5,1),xl,xr); // relu(d2) -> proj d3 (pitch 16)
  k_agg<15,16,16><<<gagg ,b256,0,stream>>>(xl,xr,off,srcs,ep5,W(5,3),selfvec+5*80,partial);
  k_final15<<<gnode,b256,0,stream>>>(partial,W(5,4),(float*)d_out);
}